// Round 7
// baseline (12819.910 us; speedup 1.0000x reference)
//
#include <hip/hip_runtime.h>

// B=8 S=1024 D1=512 D2=768 H=8 L=3 K=8192 DFF=3072, dk=96, M=B*S=8192
// Inputs: float32 (mask int32), dict order (size-verified). Outputs: FLOAT32
// (R6 forensics: bf16 writes read as fp32 put perp≈8192 at fp32 index NMe/2
// inside chunk 0 -> the exact 8192.000113 signature).
#define MROWS 8192
#define DMODEL 768
#define NEGV -1000000000.0f

__device__ __forceinline__ float block_sum(float v){
    __shared__ float red[4];
    #pragma unroll
    for (int o=32;o;o>>=1) v += __shfl_xor(v,o,64);
    int t = threadIdx.x;
    if ((t&63)==0) red[t>>6]=v;
    __syncthreads();
    v = red[0]+red[1]+red[2]+red[3];
    __syncthreads();
    return v;
}

// ---------------- GEMM: C[M,N] = act(A[M,K] @ W[K,N] + bias (+residual) (+C)) ----------
template<int ACT_GELU, int STORE_T, int ACCUM>
__global__ __launch_bounds__(256)
void gemm_kernel(const float* __restrict__ A, const float* __restrict__ W,
                 const float* __restrict__ bias, const float* __restrict__ residual,
                 float* __restrict__ C, int M, int N, int Kd, int ldW) {
    __shared__ float As[16][132];   // [k][m]
    __shared__ float Ws[16][132];   // [k][n]
    const int t  = threadIdx.x;
    const int m0 = blockIdx.x*128, n0 = blockIdx.y*128;
    const int mr = (t>>4)*8, nc = (t&15)*8;
    float acc[8][8] = {};
    for (int k0=0; k0<Kd; k0+=16) {
        #pragma unroll
        for (int p=0;p<8;p++){
            int e = t + 256*p;
            int i = e>>4, j = e&15;          // A tile 128x16
            As[j][i] = A[(size_t)(m0+i)*Kd + k0+j];
            int i2 = e>>7, j2 = e&127;       // W tile 16x128
            Ws[i2][j2] = W[(size_t)(k0+i2)*ldW + n0 + j2];
        }
        __syncthreads();
        #pragma unroll
        for (int kk=0;kk<16;kk++){
            float a[8], w[8];
            *(float4*)&a[0] = *(const float4*)&As[kk][mr];
            *(float4*)&a[4] = *(const float4*)&As[kk][mr+4];
            *(float4*)&w[0] = *(const float4*)&Ws[kk][nc];
            *(float4*)&w[4] = *(const float4*)&Ws[kk][nc+4];
            #pragma unroll
            for (int i=0;i<8;i++)
                #pragma unroll
                for (int j=0;j<8;j++) acc[i][j] += a[i]*w[j];
        }
        __syncthreads();
    }
    #pragma unroll
    for (int i=0;i<8;i++){
        int m = m0 + mr + i;
        #pragma unroll
        for (int j=0;j<8;j++){
            int n = n0 + nc + j;
            float v = acc[i][j];
            if (bias)      v += bias[n];
            if (residual)  v += residual[(size_t)m*N + n];
            if (ACT_GELU)  v = 0.5f*v*(1.0f + erff(v*0.70710678118654752f));
            if (STORE_T)      C[(size_t)n*M + m] = v;
            else if (ACCUM)   C[(size_t)m*N + n] += v;
            else              C[(size_t)m*N + n] = v;
        }
    }
}

// ---------------- LayerNorm over rows of 768 (safe in-place) ----------------
__global__ __launch_bounds__(256)
void ln_kernel(const float* __restrict__ X, const float* __restrict__ g,
               const float* __restrict__ b, float* __restrict__ Y) {
    int row = blockIdx.x, t = threadIdx.x;
    const float* x = X + (size_t)row*DMODEL;
    float v0 = x[t], v1 = x[t+256], v2 = x[t+512];
    float mean = block_sum(v0+v1+v2) * (1.0f/768.0f);
    float d0=v0-mean, d1=v1-mean, d2=v2-mean;
    float var = block_sum(d0*d0+d1*d1+d2*d2) * (1.0f/768.0f);
    float inv = rsqrtf(var + 1e-5f);
    float* y = Y + (size_t)row*DMODEL;
    y[t]     = d0*inv*g[t]     + b[t];
    y[t+256] = d1*inv*g[t+256] + b[t+256];
    y[t+512] = d2*inv*g[t+512] + b[t+512];
}

// ---------------- Flash attention (fp32), 4-batch half, ctx in-place over Q ------------
__global__ __launch_bounds__(256)
void flash_attn(float* __restrict__ QC, const float* __restrict__ Kg,
                const float* __restrict__ Vg, const int* __restrict__ mask) {
    __shared__ float As[16][132];
    __shared__ float Bs[16][132];
    __shared__ float Vs[16][100];
    const int t = threadIdx.x;
    const int bid = blockIdx.x;
    const int qt = bid & 7, hh = (bid>>3)&7, b = bid>>6;   // b in [0,4)
    const int mr = (t>>4)*8, tc = t&15, nc = tc*8, oc = tc*6;
    const size_t qbase = ((size_t)(b*1024 + qt*128))*768 + hh*96;
    const size_t kbase = ((size_t)(b*1024))*768 + hh*96;
    const float scale = 0.10206207261596575f; // 1/sqrt(96)
    float O[8][6] = {};
    float mrow[8], lrow[8];
    #pragma unroll
    for (int i=0;i<8;i++){ mrow[i] = -3.0e38f; lrow[i] = 0.f; }

    for (int kt=0; kt<8; kt++){
        float acc[8][8] = {};
        for (int k0=0; k0<96; k0+=16){
            #pragma unroll
            for (int p=0;p<8;p++){
                int e = t + 256*p;
                int r = e>>4, dj = e&15;
                As[dj][r] = QC[qbase + (size_t)r*768 + k0 + dj];
                Bs[dj][r] = Kg[kbase + (size_t)(kt*128 + r)*768 + k0 + dj];
            }
            __syncthreads();
            #pragma unroll
            for (int dj=0;dj<16;dj++){
                float a[8], w[8];
                *(float4*)&a[0] = *(const float4*)&As[dj][mr];
                *(float4*)&a[4] = *(const float4*)&As[dj][mr+4];
                *(float4*)&w[0] = *(const float4*)&Bs[dj][nc];
                *(float4*)&w[4] = *(const float4*)&Bs[dj][nc+4];
                #pragma unroll
                for (int i=0;i<8;i++)
                    #pragma unroll
                    for (int j=0;j<8;j++) acc[i][j] += a[i]*w[j];
            }
            __syncthreads();
        }
        int mv[8];
        #pragma unroll
        for (int j=0;j<8;j++) mv[j] = mask[b*1024 + kt*128 + nc + j];
        #pragma unroll
        for (int i=0;i<8;i++)
            #pragma unroll
            for (int j=0;j<8;j++){
                float s = acc[i][j]*scale;
                acc[i][j] = (mv[j]==0) ? NEGV : s;
            }
        float alpha[8];
        #pragma unroll
        for (int i=0;i<8;i++){
            float mx = acc[i][0];
            #pragma unroll
            for (int j=1;j<8;j++) mx = fmaxf(mx, acc[i][j]);
            #pragma unroll
            for (int o=1;o<16;o<<=1) mx = fmaxf(mx, __shfl_xor(mx,o,16));
            float mnew = fmaxf(mrow[i], mx);
            float al = __expf(mrow[i] - mnew);
            float ls = 0.f;
            #pragma unroll
            for (int j=0;j<8;j++){ float p = __expf(acc[i][j]-mnew); acc[i][j]=p; ls += p; }
            #pragma unroll
            for (int o=1;o<16;o<<=1) ls += __shfl_xor(ls,o,16);
            lrow[i] = lrow[i]*al + ls;
            mrow[i] = mnew;
            alpha[i] = al;
        }
        #pragma unroll
        for (int i=0;i<8;i++)
            #pragma unroll
            for (int j=0;j<6;j++) O[i][j] *= alpha[i];
        for (int c=0;c<8;c++){
            __syncthreads();
            for (int e=t; e<16*96; e+=256){
                int kk = e/96, d = e%96;
                Vs[kk][d] = Vg[kbase + (size_t)(kt*128 + c*16 + kk)*768 + d];
            }
            __syncthreads();
            #pragma unroll
            for (int kk=0; kk<16; kk++){
                const int src = 2*c + (kk>>3);
                float vfrag[6];
                *(float2*)&vfrag[0] = *(const float2*)&Vs[kk][oc];
                *(float2*)&vfrag[2] = *(const float2*)&Vs[kk][oc+2];
                *(float2*)&vfrag[4] = *(const float2*)&Vs[kk][oc+4];
                #pragma unroll
                for (int i=0;i<8;i++){
                    float p = __shfl(acc[i][kk&7], src, 16);
                    #pragma unroll
                    for (int j=0;j<6;j++) O[i][j] += p*vfrag[j];
                }
            }
        }
        __syncthreads();
    }
    #pragma unroll
    for (int i=0;i<8;i++){
        float rl = 1.0f / lrow[i];
        #pragma unroll
        for (int j=0;j<6;j++)
            QC[qbase + (size_t)(mr+i)*768 + oc + j] = O[i][j]*rl;
    }
}

// ---------------- VQ pass1: per-row Z and argmax over 8192 codes ----------------
__global__ __launch_bounds__(256)
void vq_pass1(const float* __restrict__ Qr, const float* __restrict__ KT,
              const float* __restrict__ tempp, float* __restrict__ zrow,
              int* __restrict__ amax) {
    __shared__ float QsT[768][20];
    __shared__ float Wm[16][4], Wz[16][4];
    __shared__ int   Wi[16][4];
    __shared__ float Mst[16], Zst[16];
    __shared__ int   Ast[16];
    const int t = threadIdx.x;
    const int r0 = blockIdx.x * 16;
    const float tinv = 1.0f / tempp[0];
    for (int e=t; e<16*768; e+=256){
        int r=e/768, d=e%768;
        QsT[d][r] = Qr[(size_t)(r0+r)*768 + d];
    }
    if (t<16){ Mst[t]=-1e30f; Zst[t]=0.f; Ast[t]=0; }
    __syncthreads();
    for (int jt=0; jt<8192; jt+=1024){
        const int j = jt + t*4;
        float acc[16][4];
        #pragma unroll
        for (int r=0;r<16;r++){ acc[r][0]=0;acc[r][1]=0;acc[r][2]=0;acc[r][3]=0; }
        for (int d=0; d<768; d++){
            float4 kv = *(const float4*)(KT + (size_t)d*8192 + j);
            #pragma unroll
            for (int g=0; g<4; g++){
                float4 q4 = *(const float4*)&QsT[d][g*4];
                float qq[4] = {q4.x,q4.y,q4.z,q4.w};
                #pragma unroll
                for (int rr=0; rr<4; rr++){
                    int r = g*4+rr;
                    acc[r][0] += qq[rr]*kv.x;
                    acc[r][1] += qq[rr]*kv.y;
                    acc[r][2] += qq[rr]*kv.z;
                    acc[r][3] += qq[rr]*kv.w;
                }
            }
        }
        #pragma unroll
        for (int r=0;r<16;r++){
            float s0=acc[r][0]*tinv, s1=acc[r][1]*tinv, s2=acc[r][2]*tinv, s3=acc[r][3]*tinv;
            float lm = s0; int li = j;
            if (s1>lm){lm=s1;li=j+1;}
            if (s2>lm){lm=s2;li=j+2;}
            if (s3>lm){lm=s3;li=j+3;}
            float lz = __expf(s0)+__expf(s1)+__expf(s2)+__expf(s3);
            #pragma unroll
            for (int o=1;o<64;o<<=1){
                float om = __shfl_xor(lm,o,64);
                int   oi = __shfl_xor(li,o,64);
                float oz = __shfl_xor(lz,o,64);
                lz += oz;
                if (om>lm || (om==lm && oi<li)){ lm=om; li=oi; }
            }
            if ((t&63)==0){ int w=t>>6; Wm[r][w]=lm; Wi[r][w]=li; Wz[r][w]=lz; }
        }
        __syncthreads();
        if (t<16){
            int r=t;
            float m=Mst[r]; int ai=Ast[r]; float z=Zst[r];
            #pragma unroll
            for (int w=0;w<4;w++){
                z += Wz[r][w];
                float om=Wm[r][w]; int oi=Wi[r][w];
                if (om>m || (om==m && oi<ai)){ m=om; ai=oi; }
            }
            Mst[r]=m; Ast[r]=ai; Zst[r]=z;
        }
        __syncthreads();
    }
    if (t<16){ zrow[r0+t]=Zst[t]; amax[r0+t]=Ast[t]; }
}

// ---------------- VQ pass2: recompute sims, accumulate avg_probs ----------------
__global__ __launch_bounds__(256)
void vq_pass2(const float* __restrict__ Qr, const float* __restrict__ KT,
              const float* __restrict__ tempp, const float* __restrict__ zrow,
              const int* __restrict__ mask, float* __restrict__ avgp) {
    __shared__ float QsT[768][20];
    const int t = threadIdx.x;
    const int r0 = blockIdx.x * 16;
    const float tinv = 1.0f / tempp[0];
    float zinv[16];
    #pragma unroll
    for (int r=0;r<16;r++)
        zinv[r] = (mask[r0+r] > 0) ? (1.0f/zrow[r0+r]) : 0.0f;
    for (int e=t; e<16*768; e+=256){
        int r=e/768, d=e%768;
        QsT[d][r] = Qr[(size_t)(r0+r)*768 + d];
    }
    __syncthreads();
    for (int jt=0; jt<8192; jt+=1024){
        const int j = jt + t*4;
        float acc[16][4];
        #pragma unroll
        for (int r=0;r<16;r++){ acc[r][0]=0;acc[r][1]=0;acc[r][2]=0;acc[r][3]=0; }
        for (int d=0; d<768; d++){
            float4 kv = *(const float4*)(KT + (size_t)d*8192 + j);
            #pragma unroll
            for (int g=0; g<4; g++){
                float4 q4 = *(const float4*)&QsT[d][g*4];
                float qq[4] = {q4.x,q4.y,q4.z,q4.w};
                #pragma unroll
                for (int rr=0; rr<4; rr++){
                    int r = g*4+rr;
                    acc[r][0] += qq[rr]*kv.x;
                    acc[r][1] += qq[rr]*kv.y;
                    acc[r][2] += qq[rr]*kv.z;
                    acc[r][3] += qq[rr]*kv.w;
                }
            }
        }
        float ap0=0,ap1=0,ap2=0,ap3=0;
        #pragma unroll
        for (int r=0;r<16;r++){
            ap0 += __expf(acc[r][0]*tinv)*zinv[r];
            ap1 += __expf(acc[r][1]*tinv)*zinv[r];
            ap2 += __expf(acc[r][2]*tinv)*zinv[r];
            ap3 += __expf(acc[r][3]*tinv)*zinv[r];
        }
        atomicAdd(&avgp[j+0], ap0);
        atomicAdd(&avgp[j+1], ap1);
        atomicAdd(&avgp[j+2], ap2);
        atomicAdd(&avgp[j+3], ap3);
    }
}

// ---------------- q_hard + quantized + idx + mse partial (fp32 outputs) ----------------
__global__ __launch_bounds__(256)
void qhard_kernel(const int* __restrict__ amax, const float* __restrict__ emb,
                  const float* __restrict__ hfin, const int* __restrict__ mask,
                  float* __restrict__ outq, float* __restrict__ outidx,
                  float* __restrict__ msum) {
    const int row = blockIdx.x, t = threadIdx.x;
    int idx = amax[row];
    idx = (idx < 0) ? 0 : (idx > 8191 ? 8191 : idx);
    const float mf = (mask[row] != 0) ? 1.0f : 0.0f;
    const float* er = emb  + (size_t)idx*768;
    const float* hr = hfin + (size_t)row*768;
    float local = 0.f;
    for (int d=t; d<768; d+=256){
        float q = er[d] * mf;
        outq[(size_t)row*768 + d] = q;
        float diff = (q - hr[d]) * mf;
        local += diff*diff;
    }
    local = block_sum(local);
    if (t==0){
        atomicAdd(msum, local);
        outidx[row] = (float)idx;
    }
}

// ---------------- finalize: entropy, loss, perplexity (fp32 outputs) ----------------
__global__ __launch_bounds__(256)
void finalize_kernel(const float* __restrict__ avgp, const float* __restrict__ msum,
                     const int* __restrict__ mask, float* __restrict__ outs) {
    const int t = threadIdx.x;
    float nv = 0.f;
    for (int i=t;i<8192;i+=256) nv += (float)mask[i];
    nv = block_sum(nv);
    const float inv = 1.0f/nv;
    float ent = 0.f;
    for (int j=t;j<8192;j+=256){
        float ap = avgp[j]*inv;
        ent -= ap*logf(ap + 1e-10f);
    }
    ent = block_sum(ent);
    if (t==0){
        float mse = msum[0]*inv;
        outs[0] = 1.25f*mse - 0.01f*ent;
        outs[1] = expf(ent);
    }
}

__global__ void diag_kernel(float* __restrict__ o, float a) {
    o[0] = a;
}

extern "C" void kernel_launch(void* const* d_in, const int* in_sizes, int n_in,
                              void* d_out, int out_size, void* d_ws, size_t ws_size,
                              hipStream_t stream) {
    const size_t NMe  = (size_t)MROWS*DMODEL;              // 6,291,456
    const size_t NEED = (32768 + 3*NMe) * sizeof(float);   // 72.13 MB
    const int    OUTN = (int)(NMe + 2 + 8192);

    // dict-order input size template (verified matching in R6)
    static const int EXP_DICT[28] = {
        4194304, 8192, 393216, 768,
        1769472, 2304, 1769472, 2304,
        1769472, 2304, 1769472, 2304,
        2304, 2304, 2304, 2304,
        7077888, 9216, 7077888, 2304,
        768, 768, 6291456,
        589824, 768, 589824, 768, 1 };
    bool okd = (n_in >= 28);
    int badk = -1;
    if (okd){
        for (int k=0;k<28;k++)
            if (in_sizes[k] != EXP_DICT[k]) { okd = false; if (badk<0) badk=k; break; }
    }
    if (!okd || ws_size < NEED || out_size < OUTN) {
        hipMemsetAsync(d_out, 0, (size_t)out_size * sizeof(float), stream);
        if (out_size >= 1)
            diag_kernel<<<dim3(1), dim3(64), 0, stream>>>((float*)d_out,
                (ws_size < NEED) ? 5000.0f :
                (out_size < OUTN) ? 6000.0f : (float)(10*(badk<0?0:badk)));
        return;
    }

    const float* x      = (const float*)d_in[0];
    const int*   mask   = (const int*)  d_in[1];
    const float* proj_W = (const float*)d_in[2];
    const float* proj_b = (const float*)d_in[3];
    const float* Wq     = (const float*)d_in[4];
    const float* bq     = (const float*)d_in[5];
    const float* Wk     = (const float*)d_in[6];
    const float* bk     = (const float*)d_in[7];
    const float* Wv     = (const float*)d_in[8];
    const float* bv     = (const float*)d_in[9];
    const float* Wo     = (const float*)d_in[10];
    const float* bo     = (const float*)d_in[11];
    const float* ln1_g  = (const float*)d_in[12];
    const float* ln1_b  = (const float*)d_in[13];
    const float* ln2_g  = (const float*)d_in[14];
    const float* ln2_b  = (const float*)d_in[15];
    const float* ffW1   = (const float*)d_in[16];
    const float* ffb1   = (const float*)d_in[17];
    const float* ffW2   = (const float*)d_in[18];
    const float* ffb2   = (const float*)d_in[19];
    const float* pre_g  = (const float*)d_in[20];
    const float* pre_b  = (const float*)d_in[21];
    const float* emb    = (const float*)d_in[22];
    const float* qW     = (const float*)d_in[23];
    const float* qb     = (const float*)d_in[24];
    const float* kW     = (const float*)d_in[25];
    const float* kb     = (const float*)d_in[26];
    const float* temp   = (const float*)d_in[27];

    float* ws = (float*)d_ws;
    float* avgp = ws;                      // 8192
    float* msum = ws + 8192;               // 16 (zeroed with avgp)
    float* zrow = ws + 8208;               // 8192
    int*   amax = (int*)(ws + 16400);      // 8192
    float* W0 = ws + 32768;                // h (residual stream), later h_final
    float* X1 = W0 + NMe;
    float* X2 = X1 + NMe;
    float* X1lo = X1, *X1hi = X1 + NMe/2;
    float* X2lo = X2, *X2hi = X2 + NMe/2;

    float* outq   = (float*)d_out;         // fp32 output buffer
    float* outs   = outq + NMe;            // loss, perplexity
    float* outidx = outs + 2;              // idx as float

    dim3 blk(256);
    dim3 g768(MROWS/128, 768/128);
    dim3 gh768(4096/128, 768/128);

    gemm_kernel<0,0,0><<<g768, blk, 0, stream>>>(x, proj_W, proj_b, nullptr, W0, MROWS, 768, 512, 768);

    for (int i=0;i<3;i++){
        const float* Wqi = Wq + (size_t)i*768*768;  const float* bqi = bq + (size_t)i*768;
        const float* Wki = Wk + (size_t)i*768*768;  const float* bki = bk + (size_t)i*768;
        const float* Wvi = Wv + (size_t)i*768*768;  const float* bvi = bv + (size_t)i*768;
        const float* Woi = Wo + (size_t)i*768*768;  const float* boi = bo + (size_t)i*768;
        for (int half=0; half<2; half++){
            float* Hh = W0 + (size_t)half*4096*768;
            const int* mh = mask + half*4096;
            gemm_kernel<0,0,0><<<gh768, blk, 0, stream>>>(Hh, Wqi, bqi, nullptr, X1lo, 4096, 768, 768, 768);
            gemm_kernel<0,0,0><<<gh768, blk, 0, stream>>>(Hh, Wki, bki, nullptr, X1hi, 4096, 768, 768, 768);
            gemm_kernel<0,0,0><<<gh768, blk, 0, stream>>>(Hh, Wvi, bvi, nullptr, X2lo, 4096, 768, 768, 768);
            flash_attn<<<dim3(256), blk, 0, stream>>>(X1lo, X1hi, X2lo, mh);
            gemm_kernel<0,0,0><<<gh768, blk, 0, stream>>>(X1lo, Woi, boi, Hh, X2hi, 4096, 768, 768, 768);
            ln_kernel<<<dim3(4096), blk, 0, stream>>>(X2hi, ln1_g + (size_t)i*768, ln1_b + (size_t)i*768, Hh);
        }
        const float* W1i = ffW1 + (size_t)i*768*3072;
        const float* b1i = ffb1 + (size_t)i*3072;
        const float* W2i = ffW2 + (size_t)i*3072*768;
        const float* b2i = ffb2 + (size_t)i*768;
        for (int c=0;c<4;c++){
            gemm_kernel<1,0,0><<<g768, blk, 0, stream>>>(W0, W1i + c*768, b1i + c*768,
                                                         nullptr, X1, MROWS, 768, 768, 3072);
            if (c==0)
                gemm_kernel<0,0,0><<<g768, blk, 0, stream>>>(X1, W2i + (size_t)c*768*768, b2i,
                                                             W0, X2, MROWS, 768, 768, 768);
            else
                gemm_kernel<0,0,1><<<g768, blk, 0, stream>>>(X1, W2i + (size_t)c*768*768, nullptr,
                                                             nullptr, X2, MROWS, 768, 768, 768);
        }
        ln_kernel<<<dim3(MROWS), blk, 0, stream>>>(X2, ln2_g + (size_t)i*768, ln2_b + (size_t)i*768, W0);
    }

    ln_kernel<<<dim3(MROWS), blk, 0, stream>>>(W0, pre_g, pre_b, W0);
    gemm_kernel<0,0,0><<<g768, blk, 0, stream>>>(W0, qW, qb, nullptr, X1, MROWS, 768, 768, 768);
    gemm_kernel<0,1,0><<<g768, blk, 0, stream>>>(emb, kW, kb, nullptr, X2, 8192, 768, 768, 768);

    hipMemsetAsync(avgp, 0, (8192+16)*sizeof(float), stream);

    vq_pass1<<<dim3(512), blk, 0, stream>>>(X1, X2, temp, zrow, amax);
    qhard_kernel<<<dim3(MROWS), blk, 0, stream>>>(amax, emb, W0, mask, outq, outidx, msum);
    vq_pass2<<<dim3(512), blk, 0, stream>>>(X1, X2, temp, zrow, mask, avgp);
    finalize_kernel<<<dim3(1), blk, 0, stream>>>(avgp, msum, mask, outs);
}